// Round 7
// baseline (263.031 us; speedup 1.0000x reference)
//
#include <hip/hip_runtime.h>
#include <hip/hip_bf16.h>

#define B_ 2
#define T_ 2048
#define D_ 1024
#define H_ 16
#define HD_ 64
#define NP_ 3
#define P_ 256

// log2(e)/sqrt(64): folded into Q in the QKV-GEMM epilogue; softmax in exp2 domain
#define SCALE2 0.18033688011112042f

typedef short bf16x8 __attribute__((ext_vector_type(8)));
typedef float f32x4 __attribute__((ext_vector_type(4)));

__device__ __forceinline__ float bf2f(__hip_bfloat16 v) { return __bfloat162float(v); }
__device__ __forceinline__ __hip_bfloat16 f2bf(float v) { return __float2bfloat16(v); }

// one v_cvt_pk_bf16_f32: dst.lo16 = bf16_rne(a), dst.hi16 = bf16_rne(b).
__device__ __forceinline__ unsigned pack2bf(float a, float b) {
    unsigned r;
    asm("v_cvt_pk_bf16_f32 %0, %1, %2" : "=v"(r) : "v"(a), "v"(b));
    return r;
}
__device__ __forceinline__ unsigned short f2bf_u(float v) {
    return (unsigned short)pack2bf(v, v);
}

#define GLOAD_LDS16(gp, lp) \
    __builtin_amdgcn_global_load_lds( \
        (const __attribute__((address_space(1))) void*)(gp), \
        (__attribute__((address_space(3))) void*)(lp), 16, 0, 0)

// ---------------------------------------------------------------------------
// Kernel 0: input dtype detect (fp32 reinterpreted as bf16 shows huge exps).
// ---------------------------------------------------------------------------
__global__ __launch_bounds__(256) void detect_kernel(
    const unsigned short* __restrict__ xs, int* __restrict__ flag)
{
    __shared__ int cnt;
    if (threadIdx.x == 0) cnt = 0;
    __syncthreads();
    int bad = 0;
    for (int i = threadIdx.x; i < 16384; i += 256) {
        int e = (xs[i] >> 7) & 0xFF;
        if (e >= 0xB8) bad++;
    }
    if (bad) atomicAdd(&cnt, bad);
    __syncthreads();
    if (threadIdx.x == 0) *flag = (cnt >= 8) ? 1 : 0;
}

// both weight matrices (qkv_w then o_w) -> bf16, 8 elements per thread
__global__ __launch_bounds__(256) void cvt16_2_kernel(
    const void* __restrict__ a, const void* __restrict__ bsrc,
    __hip_bfloat16* __restrict__ da, __hip_bfloat16* __restrict__ db,
    int na, int ntot, const int* __restrict__ flag)
{
    int i8 = (blockIdx.x * 256 + threadIdx.x) * 8;
    if (i8 >= ntot) return;
    int f = *flag;
    const void* src; __hip_bfloat16* dst; int off;
    if (i8 < na) { src = a; dst = da; off = i8; }
    else         { src = bsrc; dst = db; off = i8 - na; }
    if (f) {
        const float4* sp = (const float4*)((const float*)src + off);
        float4 v0 = sp[0], v1 = sp[1];
        uint4 o;
        o.x = pack2bf(v0.x, v0.y);
        o.y = pack2bf(v0.z, v0.w);
        o.z = pack2bf(v1.x, v1.y);
        o.w = pack2bf(v1.z, v1.w);
        *(uint4*)(dst + off) = o;
    } else {
        *(uint4*)(dst + off) = *(const uint4*)((const __hip_bfloat16*)src + off);
    }
}

// all 7 small fp32 parameter arrays in one launch -> contiguous fp32 block
__global__ __launch_bounds__(256) void cvt_small_kernel(
    const void* __restrict__ g,  const void* __restrict__ b,
    const void* __restrict__ n1, const void* __restrict__ n2,
    const void* __restrict__ ang, const void* __restrict__ gt,
    const void* __restrict__ bi,
    float* __restrict__ dst, const int* __restrict__ flag)
{
    int i = blockIdx.x * 256 + threadIdx.x;
    if (i >= 11008) return;
    const void* src; int off;
    if      (i < 1024) { src = g;   off = i; }
    else if (i < 2048) { src = b;   off = i - 1024; }
    else if (i < 3072) { src = n1;  off = i - 2048; }
    else if (i < 4096) { src = n2;  off = i - 3072; }
    else if (i < 4864) { src = ang; off = i - 4096; }
    else if (i < 7936) { src = gt;  off = i - 4864; }
    else               { src = bi;  off = i - 7936; }
    dst[i] = (*flag) ? ((const float*)src)[off]
                     : bf2f(((const __hip_bfloat16*)src)[off]);
}

// ---------------------------------------------------------------------------
// Kernel 1: h = rmsnorm(x,w)*gamma+beta (bf16 out, packed dword stores).
// ---------------------------------------------------------------------------
__global__ __launch_bounds__(256) void rmsnorm1_kernel(
    const void* __restrict__ xraw,
    const float* __restrict__ gamma,
    const float* __restrict__ beta,
    const float* __restrict__ w,
    const int* __restrict__ flag,
    __hip_bfloat16* __restrict__ out)
{
    int row = blockIdx.x;
    int t = threadIdx.x;
    int f = *flag;
    float eps = f ? 1.1920929e-7f : 0.0078125f;
    float v[4];
    if (f) {
        const float4 xv = ((const float4*)((const float*)xraw + (size_t)row * D_))[t];
        v[0] = xv.x; v[1] = xv.y; v[2] = xv.z; v[3] = xv.w;
    } else {
        const uint2 u = ((const uint2*)((const __hip_bfloat16*)xraw + (size_t)row * D_))[t];
        v[0] = __uint_as_float(u.x << 16);
        v[1] = __uint_as_float(u.x & 0xffff0000u);
        v[2] = __uint_as_float(u.y << 16);
        v[3] = __uint_as_float(u.y & 0xffff0000u);
    }
    float ss = 0.f;
#pragma unroll
    for (int c = 0; c < 4; c++) ss += v[c] * v[c];
#pragma unroll
    for (int m = 32; m; m >>= 1) ss += __shfl_xor(ss, m, 64);
    __shared__ float red[4];
    int wv = t >> 6;
    if ((t & 63) == 0) red[wv] = ss;
    __syncthreads();
    float scale = rsqrtf((red[0] + red[1] + red[2] + red[3]) * (1.0f / D_) + eps);
    float o[4];
#pragma unroll
    for (int c = 0; c < 4; c++) {
        int e = t * 4 + c;
        o[c] = v[c] * scale * w[e] * gamma[e] + beta[e];
    }
    uint2 pkd;
    pkd.x = pack2bf(o[0], o[1]);
    pkd.y = pack2bf(o[2], o[3]);
    *(uint2*)(out + (size_t)row * D_ + t * 4) = pkd;
}

// ---------------------------------------------------------------------------
// Kernel 2: C = A @ B^T bf16 out. 128x128, BK=32, global_load_lds width=16.
// ---------------------------------------------------------------------------
__global__ __launch_bounds__(256) void gemm_bt_bf16_kernel(
    const __hip_bfloat16* __restrict__ A,
    const __hip_bfloat16* __restrict__ Bm,
    __hip_bfloat16* __restrict__ C,
    int M, int N, int K, int nscale, float qscale)
{
    __shared__ __attribute__((aligned(16))) __hip_bfloat16 As[128 * 32];
    __shared__ __attribute__((aligned(16))) __hip_bfloat16 Bs[128 * 32];
    int tid = threadIdx.x;
    int bm = blockIdx.y, bn = blockIdx.x;
    int lane = tid & 63, wv = tid >> 6;
    int wm = wv >> 1, wn = wv & 1;
    int q = lane >> 4, mr = lane & 15;

    f32x4 acc[4][4] = {};

    for (int k0 = 0; k0 < K; k0 += 32) {
#pragma unroll
        for (int s = 0; s < 2; s++) {
            int e = (s * 256 + tid) * 8;
            int r = e >> 5, c = e & 31;
            GLOAD_LDS16(&A[(size_t)(bm * 128 + r) * K + k0 + c], &As[e]);
            GLOAD_LDS16(&Bm[(size_t)(bn * 128 + r) * K + k0 + c], &Bs[e]);
        }
        __syncthreads();
        bf16x8 af[4], bfr[4];
#pragma unroll
        for (int i = 0; i < 4; i++)
            af[i] = *(const bf16x8*)(&As[(wm * 64 + i * 16 + mr) * 32 + q * 8]);
#pragma unroll
        for (int j = 0; j < 4; j++)
            bfr[j] = *(const bf16x8*)(&Bs[(wn * 64 + j * 16 + mr) * 32 + q * 8]);
#pragma unroll
        for (int i = 0; i < 4; i++)
#pragma unroll
            for (int j = 0; j < 4; j++)
                acc[i][j] = __builtin_amdgcn_mfma_f32_16x16x32_bf16(af[i], bfr[j], acc[i][j], 0, 0, 0);
        __syncthreads();
    }

#pragma unroll
    for (int i = 0; i < 4; i++)
#pragma unroll
        for (int r = 0; r < 4; r++) {
            int m = bm * 128 + wm * 64 + i * 16 + q * 4 + r;
#pragma unroll
            for (int j = 0; j < 4; j++) {
                int n = bn * 128 + wn * 64 + j * 16 + mr;
                float vv = acc[i][j][r];
                if (n < nscale) vv *= qscale;
                ((unsigned short*)C)[(size_t)m * N + n] = f2bf_u(vv);
            }
        }
}

// Same GEMM, residual read from raw input (flag-branched dtype) + fp32 out.
__global__ __launch_bounds__(256) void gemm_bt_resid_kernel(
    const __hip_bfloat16* __restrict__ A,
    const __hip_bfloat16* __restrict__ Bm,
    const void* __restrict__ xraw,
    const int* __restrict__ flag,
    float* __restrict__ C,
    int M, int N, int K)
{
    __shared__ __attribute__((aligned(16))) __hip_bfloat16 As[128 * 32];
    __shared__ __attribute__((aligned(16))) __hip_bfloat16 Bs[128 * 32];
    int tid = threadIdx.x;
    int bm = blockIdx.y, bn = blockIdx.x;
    int lane = tid & 63, wv = tid >> 6;
    int wm = wv >> 1, wn = wv & 1;
    int q = lane >> 4, mr = lane & 15;
    int f = *flag;

    f32x4 acc[4][4] = {};

    for (int k0 = 0; k0 < K; k0 += 32) {
#pragma unroll
        for (int s = 0; s < 2; s++) {
            int e = (s * 256 + tid) * 8;
            int r = e >> 5, c = e & 31;
            GLOAD_LDS16(&A[(size_t)(bm * 128 + r) * K + k0 + c], &As[e]);
            GLOAD_LDS16(&Bm[(size_t)(bn * 128 + r) * K + k0 + c], &Bs[e]);
        }
        __syncthreads();
        bf16x8 af[4], bfr[4];
#pragma unroll
        for (int i = 0; i < 4; i++)
            af[i] = *(const bf16x8*)(&As[(wm * 64 + i * 16 + mr) * 32 + q * 8]);
#pragma unroll
        for (int j = 0; j < 4; j++)
            bfr[j] = *(const bf16x8*)(&Bs[(wn * 64 + j * 16 + mr) * 32 + q * 8]);
#pragma unroll
        for (int i = 0; i < 4; i++)
#pragma unroll
            for (int j = 0; j < 4; j++)
                acc[i][j] = __builtin_amdgcn_mfma_f32_16x16x32_bf16(af[i], bfr[j], acc[i][j], 0, 0, 0);
        __syncthreads();
    }

#pragma unroll
    for (int i = 0; i < 4; i++)
#pragma unroll
        for (int r = 0; r < 4; r++) {
            int m = bm * 128 + wm * 64 + i * 16 + q * 4 + r;
#pragma unroll
            for (int j = 0; j < 4; j++) {
                int n = bn * 128 + wn * 64 + j * 16 + mr;
                size_t idx = (size_t)m * N + n;
                float rv = f ? ((const float*)xraw)[idx]
                             : bf2f(((const __hip_bfloat16*)xraw)[idx]);
                C[idx] = rv + acc[i][j][r];
            }
        }
}

// ---------------------------------------------------------------------------
// Kernel 3: causal flash attention, r12 = r9 (best, 46.5us) + latency surgery.
// r11 (in-reg PV) regressed: longer MFMA dep chains. r5-r11 synthesis: no pipe
// saturated, wall ~ span(33 slots) x ~3.4k cyc/slot -> per-iteration latency
// chain (vmcnt stall at stage + barrier skew + per-iter address recompute).
// Changes vs r9 (math bit-identical):
//  1) 2-deep K/V prefetch: tile s+2 loads issued at top of iter s, staged at
//     end of iter s+1 -> a full iteration in flight before the vmcnt wait.
//  2) loop unrolled by 2 with compile-time buf: all LDS addresses become
//     loop-invariant base + immediate (ds offset:N); dbuf toggle costs 0 VALU.
//  3) global prefetch pointers advance by += 64*rs3 (no per-iter remultiply).
// Grid: 1024 balanced blocks (r6 mapping), 40KB LDS.
// ---------------------------------------------------------------------------
__global__ __launch_bounds__(256, 4) void attn_kernel(
    const __hip_bfloat16* __restrict__ qkv,
    __hip_bfloat16* __restrict__ attn_out)
{
    __shared__ __attribute__((aligned(16))) __hip_bfloat16 Ks[2][64 * 64];
    __shared__ __attribute__((aligned(16))) __hip_bfloat16 Vts[2][64 * 64]; // [dim][key]
    __shared__ __attribute__((aligned(16))) unsigned int Pd[4 * 512];      // P^T, 2KB/wave

    int id = blockIdx.x;                       // 0..1023
    int half = (id ^ (id >> 8)) & 1;
    int w4 = (id >> 1) & 15;
    int qt = half ? 31 - w4 : w4;              // query tile 0..31
    int bh = (id >> 5) & 31;
    int b = bh >> 4, h = bh & 15;
    int tid = threadIdx.x, lane = tid & 63, wv = tid >> 6;
    int q = lane >> 4, mr = lane & 15;
    int m8 = mr & 7;

    const size_t rs3 = 3 * D_;
    const __hip_bfloat16* qp = qkv + (size_t)(b * T_) * rs3 + h * HD_;
    const __hip_bfloat16* kp = qp + D_;
    const __hip_bfloat16* vp = qp + 2 * D_;

    // staging roles
    int sr = tid >> 2;              // K row (key) 0..63
    int sc = (tid & 3) * 16;        // K col start
    int lc0 = sc >> 3;
    int swk = sr & 7;
    int kk_ = (tid & 31) * 2;       // V key (even)
    int dd = (tid >> 5) * 8;        // V dim chunk base
    int vlc = kk_ >> 3, voff = kk_ & 7;

    // ---- hoisted loop-invariant LDS indices (halfwords / dwords) ----
    const int kfA = mr * 64 + ((q ^ m8) * 8);        // K/V frag col A (+ jn*1024 / dt*1024)
    const int kfB = mr * 64 + (((4 + q) ^ m8) * 8);  // K/V frag col B
    const int ksw0 = sr * 64 + ((lc0 ^ swk) * 8);    // K stage slots
    const int ksw1 = sr * 64 + (((lc0 + 1) ^ swk) * 8);
    int vsw[8];
#pragma unroll
    for (int i = 0; i < 8; i++)
        vsw[i] = ((dd + i) * 64 + ((vlc ^ i) * 8 + voff)) >> 1;   // V stage dword slots
    int pw_[4];
#pragma unroll
    for (int jn = 0; jn < 4; jn++)
        pw_[jn] = mr * 32 + (((2 * jn + (q >> 1)) ^ m8) << 2) + 2 * (q & 1);
    const int pr0 = mr * 32 + ((q ^ m8) << 2);       // P read kk=0
    const int pr1 = mr * 32 + (((4 + q) ^ m8) << 2); // P read kk=1

    // Q fragments: lane holds Q row (wv*16 + mr); these are the B-operand
    bf16x8 aq0, aq1;
    {
        const __hip_bfloat16* qrow = qp + (size_t)(qt * 64 + wv * 16 + mr) * rs3;
        aq0 = *(const bf16x8*)(qrow + q * 8);
        aq1 = *(const bf16x8*)(qrow + 32 + q * 8);
    }

    float l_part = 0.f;
    f32x4 o_acc[4] = {};
    unsigned int* Pw = &Pd[wv * 512];
    int qloc = wv * 16 + mr;

#define ATTN_STAGE(BUF, K0, K1, V0, V1)                                          \
    {                                                                            \
        *(bf16x8*)(&Ks[BUF][ksw0]) = (K0);                                       \
        *(bf16x8*)(&Ks[BUF][ksw1]) = (K1);                                       \
        unsigned int* vd_ = (unsigned int*)&Vts[BUF][0];                         \
        union { bf16x8 v; unsigned u[4]; } ua_, ub_;                             \
        ua_.v = (V0); ub_.v = (V1);                                              \
        _Pragma("unroll")                                                        \
        for (int w_ = 0; w_ < 4; w_++) {                                         \
            unsigned lo_ = __builtin_amdgcn_perm(ub_.u[w_], ua_.u[w_], 0x05040100u); \
            unsigned hi_ = __builtin_amdgcn_perm(ub_.u[w_], ua_.u[w_], 0x07060302u); \
            vd_[vsw[2 * w_]] = lo_;                                              \
            vd_[vsw[2 * w_ + 1]] = hi_;                                          \
        }                                                                        \
    }

#define ATTN_COMPUTE(BUF, SCUR)                                                  \
    {                                                                            \
        f32x4 sv[4] = {};                                                        \
        _Pragma("unroll")                                                        \
        for (int jn = 0; jn < 4; jn++)                                           \
            sv[jn] = __builtin_amdgcn_mfma_f32_16x16x32_bf16(                    \
                *(const bf16x8*)(&Ks[BUF][kfA + jn * 1024]), aq0, sv[jn], 0, 0, 0); \
        _Pragma("unroll")                                                        \
        for (int jn = 0; jn < 4; jn++)                                           \
            sv[jn] = __builtin_amdgcn_mfma_f32_16x16x32_bf16(                    \
                *(const bf16x8*)(&Ks[BUF][kfB + jn * 1024]), aq1, sv[jn], 0, 0, 0); \
        if ((SCUR) == qt) {                                                      \
            _Pragma("unroll")                                                    \
            for (int jn = 0; jn < 4; jn++)                                       \
                _Pragma("unroll")                                                \
                for (int r = 0; r < 4; r++)                                      \
                    if (jn * 16 + q * 4 + r > qloc) sv[jn][r] = -1e30f;          \
        }                                                                        \
        _Pragma("unroll")                                                        \
        for (int jn = 0; jn < 4; jn++)                                           \
            _Pragma("unroll")                                                    \
            for (int r = 0; r < 4; r++) {                                        \
                float p_ = exp2f(sv[jn][r]);                                     \
                sv[jn][r] = p_;                                                  \
                l_part += p_;                                                    \
            }                                                                    \
        _Pragma("unroll")                                                        \
        for (int jn = 0; jn < 4; jn++) {                                         \
            uint2 val_;                                                          \
            val_.x = pack2bf(sv[jn][0], sv[jn][1]);                              \
            val_.y = pack2bf(sv[jn][2], sv[jn][3]);                              \
            *(uint2*)(&Pw[pw_[jn]]) = val_;                                      \
        }                                                                        \
        {                                                                        \
            bf16x8 bp0 = *(const bf16x8*)(&Pw[pr0]);                             \
            _Pragma("unroll")                                                    \
            for (int dt = 0; dt < 4; dt++)                                       \
                o_acc[dt] = __builtin_amdgcn_mfma_f32_16x16x32_bf16(             \
                    *(const bf16x8*)(&Vts[BUF][kfA + dt * 1024]), bp0, o_acc[dt], 0, 0, 0); \
            bf16x8 bp1 = *(const bf16x8*)(&Pw[pr1]);                             \
            _Pragma("unroll")                                                    \
            for (int dt = 0; dt < 4; dt++)                                       \
                o_acc[dt] = __builtin_amdgcn_mfma_f32_16x16x32_bf16(             \
                    *(const bf16x8*)(&Vts[BUF][kfB + dt * 1024]), bp1, o_acc[dt], 0, 0, 0); \
        }                                                                        \
    }

    // ---- prologue: load+stage tile0 -> buf0; load tile1 -> reg set A ----
    const __hip_bfloat16* kg = kp + (size_t)sr * rs3 + sc;
    const __hip_bfloat16* vg = vp + (size_t)kk_ * rs3 + dd;
    const ptrdiff_t KVS = (ptrdiff_t)64 * rs3;

    {
        bf16x8 k0 = *(const bf16x8*)(kg);
        bf16x8 k1 = *(const bf16x8*)(kg + 8);
        bf16x8 v0 = *(const bf16x8*)(vg);
        bf16x8 v1 = *(const bf16x8*)(vg + rs3);
        ATTN_STAGE(0, k0, k1, v0, v1);
    }
    bf16x8 ka0, ka1, va0, va1, kb0, kb1, vb0, vb1;
    if (qt >= 1) {
        kg += KVS; vg += KVS;
        ka0 = *(const bf16x8*)(kg); ka1 = *(const bf16x8*)(kg + 8);
        va0 = *(const bf16x8*)(vg); va1 = *(const bf16x8*)(vg + rs3);
    }
    __syncthreads();

    // ---- main loop: pairs of iterations with compile-time buf ----
    int scur = 0;
    for (; scur + 1 <= qt; scur += 2) {
        // even iter: buf0, stage set A (tile scur+1), load tile scur+2 -> B
        if (scur + 2 <= qt) {
            kg += KVS; vg += KVS;
            kb0 = *(const bf16x8*)(kg); kb1 = *(const bf16x8*)(kg + 8);
            vb0 = *(const bf16x8*)(vg); vb1 = *(const bf16x8*)(vg + rs3);
        }
        ATTN_COMPUTE(0, scur);
        ATTN_STAGE(1, ka0, ka1, va0, va1);
        __syncthreads();

        // odd iter: buf1, stage set B (tile scur+2), load tile scur+3 -> A
        if (scur + 3 <= qt) {
            kg += KVS; vg += KVS;
            ka0 = *(const bf16x8*)(kg); ka1 = *(const bf16x8*)(kg + 8);
            va0 = *(const bf16x8*)(vg); va1 = *(const bf16x8*)(vg + rs3);
        }
        ATTN_COMPUTE(1, scur + 1);
        if (scur + 1 < qt) {
            ATTN_STAGE(0, kb0, kb1, vb0, vb1);
        }
        __syncthreads();
    }
    // tail: qt even -> one more iteration at s = qt (buf0, already staged)
    if (!(qt & 1)) {
        ATTN_COMPUTE(0, qt);
    }

#undef ATTN_COMPUTE
#undef ATTN_STAGE

    // final l reduction across the 4 key-quarters of each query
    float l_run = l_part;
    l_run += __shfl_xor(l_run, 16, 64);
    l_run += __shfl_xor(l_run, 32, 64);

    // output: dim = dt*16 + q*4 + r, query = mr
    {
        float inv = 1.0f / l_run;
        int trow = qt * 64 + wv * 16 + mr;
        __hip_bfloat16* op = attn_out + (size_t)(b * T_ + trow) * D_ + h * HD_;
#pragma unroll
        for (int dt = 0; dt < 4; dt++) {
            uint2 val;
            val.x = pack2bf(o_acc[dt][0] * inv, o_acc[dt][1] * inv);
            val.y = pack2bf(o_acc[dt][2] * inv, o_acc[dt][3] * inv);
            *(uint2*)(op + dt * 16 + q * 4) = val;
        }
    }
}

// ---------------------------------------------------------------------------
// Kernel 5: h = rmsnorm(xn,w2)*gamma+beta; rotations+silu; out = xn + r - h.
// ---------------------------------------------------------------------------
__global__ __launch_bounds__(256) void final_kernel(
    const float* __restrict__ xn,
    const float* __restrict__ gamma,
    const float* __restrict__ beta,
    const float* __restrict__ w2,
    const float* __restrict__ angles,
    const float* __restrict__ gate,
    const float* __restrict__ bias,
    const int* __restrict__ pi,
    const int* __restrict__ pj,
    const int* __restrict__ flag,
    void* __restrict__ outp)
{
    __shared__ float rbuf[D_];
    __shared__ float red[4];
    int row = blockIdx.x, t = threadIdx.x;
    int f = *flag;
    float eps = f ? 1.1920929e-7f : 0.0078125f;
    const float4 xv = ((const float4*)(xn + (size_t)row * D_))[t];
    float x4[4] = {xv.x, xv.y, xv.z, xv.w};
    float ss = 0.f;
#pragma unroll
    for (int c = 0; c < 4; c++) ss += x4[c] * x4[c];
#pragma unroll
    for (int m = 32; m; m >>= 1) ss += __shfl_xor(ss, m, 64);
    int wv = t >> 6;
    if ((t & 63) == 0) red[wv] = ss;
    __syncthreads();
    float scale = rsqrtf((red[0] + red[1] + red[2] + red[3]) * (1.0f / D_) + eps);
    float hloc[4];
#pragma unroll
    for (int c = 0; c < 4; c++) {
        int e = t * 4 + c;
        float hv = x4[c] * scale * w2[e] * gamma[e] + beta[e];
        hloc[c] = hv;
        rbuf[e] = hv;
    }
    __syncthreads();
    for (int p = 0; p < NP_; p++) {
        float a = angles[p * P_ + t];
        float ca = __cosf(a), sa = __sinf(a);
        int ip = pi[p * P_ + t], jp = pj[p * P_ + t];
        float hi = rbuf[ip], hj = rbuf[jp];
        rbuf[ip] = hi * ca - hj * sa;
        rbuf[jp] = hi * sa + hj * ca;
        __syncthreads();
#pragma unroll
        for (int c = 0; c < 4; c++) {
            int e = t * 4 + c;
            float v = rbuf[e] * gate[p * D_ + e] + bias[p * D_ + e];
            rbuf[e] = v / (1.f + __expf(-v));
        }
        __syncthreads();
    }
#pragma unroll
    for (int c = 0; c < 4; c++) {
        int e = t * 4 + c;
        float ov = x4[c] + rbuf[e] - hloc[c];
        size_t idx = (size_t)row * D_ + e;
        if (f) ((float*)outp)[idx] = ov;
        else   ((__hip_bfloat16*)outp)[idx] = f2bf(ov);
    }
}

// ---------------------------------------------------------------------------
extern "C" void kernel_launch(void* const* d_in, const int* in_sizes, int n_in,
                              void* d_out, int out_size, void* d_ws, size_t ws_size,
                              hipStream_t stream)
{
    const void* x      = d_in[0];
    const void* gamma  = d_in[1];
    const void* beta   = d_in[2];
    const void* qkv_w  = d_in[3];
    const void* o_w    = d_in[4];
    const void* n1w    = d_in[5];
    const void* n2w    = d_in[6];
    const void* angles = d_in[7];
    const void* gate   = d_in[8];
    const void* bias   = d_in[9];
    const int* pi = (const int*)d_in[10];
    const int* pj = (const int*)d_in[11];

    const int M = B_ * T_;
    char* ws = (char*)d_ws;
    const size_t MB = 1u << 20;
    int*   flag   = (int*)ws;
    float* smalls = (float*)(ws + 4096);       // 11008 floats, 44 KB
    float* gf   = smalls;
    float* bf   = smalls + 1024;
    float* n1f  = smalls + 2048;
    float* n2f  = smalls + 3072;
    float* angf = smalls + 4096;
    float* gtf  = smalls + 4864;
    float* bif  = smalls + 7936;
    __hip_bfloat16* wbf  = (__hip_bfloat16*)(ws + 17 * MB);  //  6 MB [3D,D]
    __hip_bfloat16* owbf = (__hip_bfloat16*)(ws + 23 * MB);  //  2 MB [D,D]
    __hip_bfloat16* h1   = (__hip_bfloat16*)(ws + 25 * MB);  //  8 MB [M,D] (h / attn out)
    __hip_bfloat16* qkv  = (__hip_bfloat16*)(ws + 33 * MB);  // 24 MB [M,3D]
    float*          xnew = (float*)         (ws + 33 * MB);  // 16 MB, aliases dead qkv

    detect_kernel<<<1, 256, 0, stream>>>((const unsigned short*)x, flag);

    cvt_small_kernel<<<43, 256, 0, stream>>>(gamma, beta, n1w, n2w, angles, gate, bias,
                                             smalls, flag);
    cvt16_2_kernel<<<(4 * D_ * D_ / 8 + 255) / 256, 256, 0, stream>>>(
        qkv_w, o_w, wbf, owbf, 3 * D_ * D_, 4 * D_ * D_, flag);

    rmsnorm1_kernel<<<M, 256, 0, stream>>>(x, gf, bf, n1f, flag, h1);

    gemm_bt_bf16_kernel<<<dim3(3 * D_ / 128, M / 128), 256, 0, stream>>>(
        h1, wbf, qkv, M, 3 * D_, D_, D_, SCALE2);

    attn_kernel<<<dim3(1024), 256, 0, stream>>>(qkv, h1);

    gemm_bt_resid_kernel<<<dim3(D_ / 128, M / 128), 256, 0, stream>>>(
        h1, owbf, x, flag, xnew, M, D_, D_);

    final_kernel<<<M, 256, 0, stream>>>(xnew, gf, bf, n2f, angf, gtf, bif,
                                        pi, pj, flag, d_out);
}

// Round 8
// 235.056 us; speedup vs baseline: 1.1190x; 1.1190x over previous
//
#include <hip/hip_runtime.h>
#include <hip/hip_bf16.h>

#define B_ 2
#define T_ 2048
#define D_ 1024
#define H_ 16
#define HD_ 64
#define NP_ 3
#define P_ 256

// log2(e)/sqrt(64): folded into Q in the QKV-GEMM epilogue; softmax in exp2 domain
#define SCALE2 0.18033688011112042f

typedef short bf16x8 __attribute__((ext_vector_type(8)));
typedef float f32x4 __attribute__((ext_vector_type(4)));

__device__ __forceinline__ float bf2f(__hip_bfloat16 v) { return __bfloat162float(v); }
__device__ __forceinline__ __hip_bfloat16 f2bf(float v) { return __float2bfloat16(v); }

// one v_cvt_pk_bf16_f32: dst.lo16 = bf16_rne(a), dst.hi16 = bf16_rne(b).
__device__ __forceinline__ unsigned pack2bf(float a, float b) {
    unsigned r;
    asm("v_cvt_pk_bf16_f32 %0, %1, %2" : "=v"(r) : "v"(a), "v"(b));
    return r;
}
__device__ __forceinline__ unsigned short f2bf_u(float v) {
    return (unsigned short)pack2bf(v, v);
}

#define GLOAD_LDS16(gp, lp) \
    __builtin_amdgcn_global_load_lds( \
        (const __attribute__((address_space(1))) void*)(gp), \
        (__attribute__((address_space(3))) void*)(lp), 16, 0, 0)

// ---------------------------------------------------------------------------
// Kernel 0: input dtype detect (fp32 reinterpreted as bf16 shows huge exps).
// ---------------------------------------------------------------------------
__global__ __launch_bounds__(256) void detect_kernel(
    const unsigned short* __restrict__ xs, int* __restrict__ flag)
{
    __shared__ int cnt;
    if (threadIdx.x == 0) cnt = 0;
    __syncthreads();
    int bad = 0;
    for (int i = threadIdx.x; i < 16384; i += 256) {
        int e = (xs[i] >> 7) & 0xFF;
        if (e >= 0xB8) bad++;
    }
    if (bad) atomicAdd(&cnt, bad);
    __syncthreads();
    if (threadIdx.x == 0) *flag = (cnt >= 8) ? 1 : 0;
}

// ---------------------------------------------------------------------------
// Merged prep kernel (one launch, all flag-dependent preprocessing):
//  blocks [0, 2048)       : qkv_w + o_w -> bf16, 8 elems/thread
//  blocks [2048, 6144)    : rmsnorm1 rows (params loaded raw w/ flag branch)
//  blocks [6144, 6187)    : 7 small fp32 param arrays -> contiguous block
// Saves 2 launch boundaries; small copies overlap under rmsnorm.
// ---------------------------------------------------------------------------
__global__ __launch_bounds__(256) void prep_kernel(
    const void* __restrict__ xraw,
    const void* __restrict__ qkvw, const void* __restrict__ ow,
    const void* __restrict__ g,  const void* __restrict__ b,
    const void* __restrict__ n1, const void* __restrict__ n2,
    const void* __restrict__ ang, const void* __restrict__ gt,
    const void* __restrict__ bi,
    const int* __restrict__ flag,
    __hip_bfloat16* __restrict__ wbf, __hip_bfloat16* __restrict__ owbf,
    float* __restrict__ smalls, __hip_bfloat16* __restrict__ out)
{
    int bid = blockIdx.x;
    int t = threadIdx.x;
    int f = *flag;

    if (bid < 2048) {
        // ---- weight conversion ----
        const int na = 3 * D_ * D_;
        int i8 = (bid * 256 + t) * 8;
        const void* src; __hip_bfloat16* dst; int off;
        if (i8 < na) { src = qkvw; dst = wbf; off = i8; }
        else         { src = ow;   dst = owbf; off = i8 - na; }
        if (f) {
            const float4* sp = (const float4*)((const float*)src + off);
            float4 v0 = sp[0], v1 = sp[1];
            uint4 o;
            o.x = pack2bf(v0.x, v0.y);
            o.y = pack2bf(v0.z, v0.w);
            o.z = pack2bf(v1.x, v1.y);
            o.w = pack2bf(v1.z, v1.w);
            *(uint4*)(dst + off) = o;
        } else {
            *(uint4*)(dst + off) = *(const uint4*)((const __hip_bfloat16*)src + off);
        }
        return;
    }
    if (bid < 6144) {
        // ---- rmsnorm1: h = rmsnorm(x,w)*gamma+beta (bf16 out) ----
        int row = bid - 2048;
        float eps = f ? 1.1920929e-7f : 0.0078125f;
        float v[4], ga[4], be[4], ww[4];
        if (f) {
            const float4 xv = ((const float4*)((const float*)xraw + (size_t)row * D_))[t];
            v[0] = xv.x; v[1] = xv.y; v[2] = xv.z; v[3] = xv.w;
            const float4 gv = ((const float4*)g)[t];
            ga[0] = gv.x; ga[1] = gv.y; ga[2] = gv.z; ga[3] = gv.w;
            const float4 bv = ((const float4*)b)[t];
            be[0] = bv.x; be[1] = bv.y; be[2] = bv.z; be[3] = bv.w;
            const float4 wv4 = ((const float4*)n1)[t];
            ww[0] = wv4.x; ww[1] = wv4.y; ww[2] = wv4.z; ww[3] = wv4.w;
        } else {
            const uint2 u = ((const uint2*)((const __hip_bfloat16*)xraw + (size_t)row * D_))[t];
            v[0] = __uint_as_float(u.x << 16);
            v[1] = __uint_as_float(u.x & 0xffff0000u);
            v[2] = __uint_as_float(u.y << 16);
            v[3] = __uint_as_float(u.y & 0xffff0000u);
#pragma unroll
            for (int c = 0; c < 4; c++) {
                int e = t * 4 + c;
                ga[c] = bf2f(((const __hip_bfloat16*)g)[e]);
                be[c] = bf2f(((const __hip_bfloat16*)b)[e]);
                ww[c] = bf2f(((const __hip_bfloat16*)n1)[e]);
            }
        }
        float ss = 0.f;
#pragma unroll
        for (int c = 0; c < 4; c++) ss += v[c] * v[c];
#pragma unroll
        for (int m = 32; m; m >>= 1) ss += __shfl_xor(ss, m, 64);
        __shared__ float red[4];
        int wv = t >> 6;
        if ((t & 63) == 0) red[wv] = ss;
        __syncthreads();
        float scale = rsqrtf((red[0] + red[1] + red[2] + red[3]) * (1.0f / D_) + eps);
        float o[4];
#pragma unroll
        for (int c = 0; c < 4; c++)
            o[c] = v[c] * scale * ww[c] * ga[c] + be[c];
        uint2 pkd;
        pkd.x = pack2bf(o[0], o[1]);
        pkd.y = pack2bf(o[2], o[3]);
        *(uint2*)(out + (size_t)row * D_ + t * 4) = pkd;
        return;
    }
    {
        // ---- small param arrays -> fp32 ----
        int i = (bid - 6144) * 256 + t;
        if (i >= 11008) return;
        const void* src; int off;
        if      (i < 1024) { src = g;   off = i; }
        else if (i < 2048) { src = b;   off = i - 1024; }
        else if (i < 3072) { src = n1;  off = i - 2048; }
        else if (i < 4096) { src = n2;  off = i - 3072; }
        else if (i < 4864) { src = ang; off = i - 4096; }
        else if (i < 7936) { src = gt;  off = i - 4864; }
        else               { src = bi;  off = i - 7936; }
        smalls[i] = f ? ((const float*)src)[off]
                      : bf2f(((const __hip_bfloat16*)src)[off]);
    }
}

// ---------------------------------------------------------------------------
// Kernel 2: C = A @ B^T bf16 out. 128x128, BK=32, global_load_lds width=16.
// Columns n < nscale get scaled by qscale (folds attention score scale into Q).
// ---------------------------------------------------------------------------
__global__ __launch_bounds__(256) void gemm_bt_bf16_kernel(
    const __hip_bfloat16* __restrict__ A,
    const __hip_bfloat16* __restrict__ Bm,
    __hip_bfloat16* __restrict__ C,
    int M, int N, int K, int nscale, float qscale)
{
    __shared__ __attribute__((aligned(16))) __hip_bfloat16 As[128 * 32];
    __shared__ __attribute__((aligned(16))) __hip_bfloat16 Bs[128 * 32];
    int tid = threadIdx.x;
    int bm = blockIdx.y, bn = blockIdx.x;
    int lane = tid & 63, wv = tid >> 6;
    int wm = wv >> 1, wn = wv & 1;
    int q = lane >> 4, mr = lane & 15;

    f32x4 acc[4][4] = {};

    for (int k0 = 0; k0 < K; k0 += 32) {
#pragma unroll
        for (int s = 0; s < 2; s++) {
            int e = (s * 256 + tid) * 8;
            int r = e >> 5, c = e & 31;
            GLOAD_LDS16(&A[(size_t)(bm * 128 + r) * K + k0 + c], &As[e]);
            GLOAD_LDS16(&Bm[(size_t)(bn * 128 + r) * K + k0 + c], &Bs[e]);
        }
        __syncthreads();
        bf16x8 af[4], bfr[4];
#pragma unroll
        for (int i = 0; i < 4; i++)
            af[i] = *(const bf16x8*)(&As[(wm * 64 + i * 16 + mr) * 32 + q * 8]);
#pragma unroll
        for (int j = 0; j < 4; j++)
            bfr[j] = *(const bf16x8*)(&Bs[(wn * 64 + j * 16 + mr) * 32 + q * 8]);
#pragma unroll
        for (int i = 0; i < 4; i++)
#pragma unroll
            for (int j = 0; j < 4; j++)
                acc[i][j] = __builtin_amdgcn_mfma_f32_16x16x32_bf16(af[i], bfr[j], acc[i][j], 0, 0, 0);
        __syncthreads();
    }

#pragma unroll
    for (int i = 0; i < 4; i++)
#pragma unroll
        for (int r = 0; r < 4; r++) {
            int m = bm * 128 + wm * 64 + i * 16 + q * 4 + r;
#pragma unroll
            for (int j = 0; j < 4; j++) {
                int n = bn * 128 + wn * 64 + j * 16 + mr;
                float vv = acc[i][j][r];
                if (n < nscale) vv *= qscale;
                ((unsigned short*)C)[(size_t)m * N + n] = f2bf_u(vv);
            }
        }
}

// ---------------------------------------------------------------------------
// o-proj GEMM, 128x64 tile: grid (N/64, M/128) = (16,32) = 512 blocks = 2/CU
// (was 256 = 1/CU -- no inter-block overlap to hide barrier drains).
// Per wave: rows wv*32..+32, all 64 cols; acc[2][4]; 3 gloads/K-step.
// Residual read from raw input (flag-branched dtype), fp32 out.
// Per-element K-order identical to the 128x128 version.
// ---------------------------------------------------------------------------
__global__ __launch_bounds__(256) void gemm_o64_resid_kernel(
    const __hip_bfloat16* __restrict__ A,
    const __hip_bfloat16* __restrict__ Bm,
    const void* __restrict__ xraw,
    const int* __restrict__ flag,
    float* __restrict__ C,
    int M, int N, int K)
{
    __shared__ __attribute__((aligned(16))) __hip_bfloat16 As[128 * 32];
    __shared__ __attribute__((aligned(16))) __hip_bfloat16 Bs[64 * 32];
    int tid = threadIdx.x;
    int bn = blockIdx.x, bm = blockIdx.y;
    int lane = tid & 63, wv = tid >> 6;
    int q = lane >> 4, mr = lane & 15;
    int f = *flag;

    f32x4 acc[2][4] = {};

    for (int k0 = 0; k0 < K; k0 += 32) {
#pragma unroll
        for (int s = 0; s < 2; s++) {
            int e = (s * 256 + tid) * 8;
            int r = e >> 5, c = e & 31;
            GLOAD_LDS16(&A[(size_t)(bm * 128 + r) * K + k0 + c], &As[e]);
        }
        {
            int e = tid * 8;
            int r = e >> 5, c = e & 31;
            GLOAD_LDS16(&Bm[(size_t)(bn * 64 + r) * K + k0 + c], &Bs[e]);
        }
        __syncthreads();
        bf16x8 af[2], bfr[4];
#pragma unroll
        for (int i = 0; i < 2; i++)
            af[i] = *(const bf16x8*)(&As[(wv * 32 + i * 16 + mr) * 32 + q * 8]);
#pragma unroll
        for (int j = 0; j < 4; j++)
            bfr[j] = *(const bf16x8*)(&Bs[(j * 16 + mr) * 32 + q * 8]);
#pragma unroll
        for (int i = 0; i < 2; i++)
#pragma unroll
            for (int j = 0; j < 4; j++)
                acc[i][j] = __builtin_amdgcn_mfma_f32_16x16x32_bf16(af[i], bfr[j], acc[i][j], 0, 0, 0);
        __syncthreads();
    }

#pragma unroll
    for (int i = 0; i < 2; i++)
#pragma unroll
        for (int r = 0; r < 4; r++) {
            int m = bm * 128 + wv * 32 + i * 16 + q * 4 + r;
#pragma unroll
            for (int j = 0; j < 4; j++) {
                int n = bn * 64 + j * 16 + mr;
                size_t idx = (size_t)m * N + n;
                float rv = f ? ((const float*)xraw)[idx]
                             : bf2f(((const __hip_bfloat16*)xraw)[idx]);
                C[idx] = rv + acc[i][j][r];
            }
        }
}

// ---------------------------------------------------------------------------
// Kernel 3: causal flash attention, r9 verbatim (best: 46.5us, VGPR 52).
// r10/r11/r12 all regressed (imbalance / longer MFMA chains / VGPR spills);
// this structure is the measured local optimum.
// Grid: 1024 balanced blocks (r6 mapping), 40KB LDS, 4 blocks/CU.
// ---------------------------------------------------------------------------
__global__ __launch_bounds__(256, 4) void attn_kernel(
    const __hip_bfloat16* __restrict__ qkv,
    __hip_bfloat16* __restrict__ attn_out)
{
    __shared__ __attribute__((aligned(16))) __hip_bfloat16 Ks[2][64 * 64];
    __shared__ __attribute__((aligned(16))) __hip_bfloat16 Vts[2][64 * 64]; // [dim][key]
    __shared__ __attribute__((aligned(16))) unsigned int Pd[4 * 512];      // P^T, 2KB/wave

    int id = blockIdx.x;                       // 0..1023
    int half = (id ^ (id >> 8)) & 1;
    int w4 = (id >> 1) & 15;
    int qt = half ? 31 - w4 : w4;              // query tile 0..31
    int bh = (id >> 5) & 31;
    int b = bh >> 4, h = bh & 15;
    int tid = threadIdx.x, lane = tid & 63, wv = tid >> 6;
    int q = lane >> 4, mr = lane & 15;
    int m8 = mr & 7;

    const size_t rs3 = 3 * D_;
    const __hip_bfloat16* qp = qkv + (size_t)(b * T_) * rs3 + h * HD_;
    const __hip_bfloat16* kp = qp + D_;
    const __hip_bfloat16* vp = qp + 2 * D_;

    // staging roles
    int sr = tid >> 2;              // K row (key) 0..63
    int sc = (tid & 3) * 16;        // K col start
    int lc0 = sc >> 3;
    int swk = sr & 7;
    int kk_ = (tid & 31) * 2;       // V key (even)
    int dd = (tid >> 5) * 8;        // V dim chunk base
    int vlc = kk_ >> 3, voff = kk_ & 7;

    // Q fragments: lane holds Q row (wv*16 + mr); these are the B-operand
    bf16x8 aq0, aq1;
    {
        const __hip_bfloat16* qrow = qp + (size_t)(qt * 64 + wv * 16 + mr) * rs3;
        aq0 = *(const bf16x8*)(qrow + q * 8);
        aq1 = *(const bf16x8*)(qrow + 32 + q * 8);
    }

    // prefetch K/V tile 0 and stage into buffer 0
    bf16x8 kr0 = *(const bf16x8*)(kp + (size_t)sr * rs3 + sc);
    bf16x8 kr1 = *(const bf16x8*)(kp + (size_t)sr * rs3 + sc + 8);
    bf16x8 vr0 = *(const bf16x8*)(vp + (size_t)kk_ * rs3 + dd);
    bf16x8 vr1 = *(const bf16x8*)(vp + (size_t)(kk_ + 1) * rs3 + dd);
    *(bf16x8*)(&Ks[0][sr * 64 + ((lc0 ^ swk) * 8)]) = kr0;
    *(bf16x8*)(&Ks[0][sr * 64 + (((lc0 + 1) ^ swk) * 8)]) = kr1;
    {
        unsigned int* vd = (unsigned int*)&Vts[0][0];
        union { bf16x8 v; unsigned u[4]; } ua, ub;
        ua.v = vr0; ub.v = vr1;
#pragma unroll
        for (int w = 0; w < 4; w++) {
            unsigned lo = __builtin_amdgcn_perm(ub.u[w], ua.u[w], 0x05040100u);
            unsigned hi = __builtin_amdgcn_perm(ub.u[w], ua.u[w], 0x07060302u);
            int i0 = 2 * w, i1 = 2 * w + 1;
            vd[((dd + i0) * 64 + ((vlc ^ i0) * 8 + voff)) >> 1] = lo;
            vd[((dd + i1) * 64 + ((vlc ^ i1) * 8 + voff)) >> 1] = hi;
        }
    }
    __syncthreads();

    float l_part = 0.f;                 // per-thread partial; reduced after loop
    f32x4 o_acc[4] = {};
    unsigned int* Pw = &Pd[wv * 512];
    int qloc = wv * 16 + mr;            // query row within 64-tile

    for (int s = 0; s <= qt; s++) {
        int buf = s & 1;

        // register prefetches for step s+1 (consumed after compute)
        if (s < qt) {
            int ktn = s + 1;
            kr0 = *(const bf16x8*)(kp + (size_t)(ktn * 64 + sr) * rs3 + sc);
            kr1 = *(const bf16x8*)(kp + (size_t)(ktn * 64 + sr) * rs3 + sc + 8);
            vr0 = *(const bf16x8*)(vp + (size_t)(ktn * 64 + kk_) * rs3 + dd);
            vr1 = *(const bf16x8*)(vp + (size_t)(ktn * 64 + kk_ + 1) * rs3 + dd);
        }

        // S^T strip: D[key][query], A = K-frag, B = Q-frag (swapped operands)
        f32x4 sv[4] = {};
        {
            const __hip_bfloat16* Kb = &Ks[buf][0];
#pragma unroll
            for (int jn = 0; jn < 4; jn++)
                sv[jn] = __builtin_amdgcn_mfma_f32_16x16x32_bf16(
                    *(const bf16x8*)(&Kb[(jn * 16 + mr) * 64 + ((q ^ m8) * 8)]),
                    aq0, sv[jn], 0, 0, 0);
#pragma unroll
            for (int jn = 0; jn < 4; jn++)
                sv[jn] = __builtin_amdgcn_mfma_f32_16x16x32_bf16(
                    *(const bf16x8*)(&Kb[(jn * 16 + mr) * 64 + (((4 + q) ^ m8) * 8)]),
                    aq1, sv[jn], 0, 0, 0);
        }

        if (s == qt) {   // causal mask: key (jn*16+q*4+r) > query (qloc)
#pragma unroll
            for (int jn = 0; jn < 4; jn++)
#pragma unroll
                for (int r = 0; r < 4; r++)
                    if (jn * 16 + q * 4 + r > qloc) sv[jn][r] = -1e30f;
        }

        // static-shift softmax: p = exp2(s); no max tracking, no rescale.
#pragma unroll
        for (int jn = 0; jn < 4; jn++)
#pragma unroll
            for (int r = 0; r < 4; r++) {
                float p = exp2f(sv[jn][r]);
                sv[jn][r] = p;
                l_part += p;
            }

        // P^T pack -> LDS: row = query (mr), dwords = key pairs, b64 writes.
        // Physical dword addr = mr*32 + ((dw4 ^ m8) << 2) + low2 (conflict-free).
#pragma unroll
        for (int jn = 0; jn < 4; jn++) {
            uint2 val;
            val.x = pack2bf(sv[jn][0], sv[jn][1]);
            val.y = pack2bf(sv[jn][2], sv[jn][3]);
            int dw4 = 2 * jn + (q >> 1);
            *(uint2*)(&Pw[mr * 32 + ((dw4 ^ m8) << 2) + 2 * (q & 1)]) = val;
        }

        // PV: O^T[dim][query] += V^T-frag (A) x P^T-frag (B)
#pragma unroll
        for (int kk = 0; kk < 2; kk++) {
            bf16x8 bp = *(const bf16x8*)(&Pw[mr * 32 + (((4 * kk + q) ^ m8) << 2)]);
#pragma unroll
            for (int dt = 0; dt < 4; dt++) {
                bf16x8 bv = *(const bf16x8*)(&Vts[buf][(dt * 16 + mr) * 64 + (((kk * 4 + q) ^ m8) * 8)]);
                o_acc[dt] = __builtin_amdgcn_mfma_f32_16x16x32_bf16(bv, bp, o_acc[dt], 0, 0, 0);
            }
        }

        // stage next tile into the other buffer
        if (s < qt) {
            *(bf16x8*)(&Ks[buf ^ 1][sr * 64 + ((lc0 ^ swk) * 8)]) = kr0;
            *(bf16x8*)(&Ks[buf ^ 1][sr * 64 + (((lc0 + 1) ^ swk) * 8)]) = kr1;
            unsigned int* vd = (unsigned int*)&Vts[buf ^ 1][0];
            union { bf16x8 v; unsigned u[4]; } ua, ub;
            ua.v = vr0; ub.v = vr1;
#pragma unroll
            for (int w = 0; w < 4; w++) {
                unsigned lo = __builtin_amdgcn_perm(ub.u[w], ua.u[w], 0x05040100u);
                unsigned hi = __builtin_amdgcn_perm(ub.u[w], ua.u[w], 0x07060302u);
                int i0 = 2 * w, i1 = 2 * w + 1;
                vd[((dd + i0) * 64 + ((vlc ^ i0) * 8 + voff)) >> 1] = lo;
                vd[((dd + i1) * 64 + ((vlc ^ i1) * 8 + voff)) >> 1] = hi;
            }
        }
        __syncthreads();
    }

    // final l reduction across the 4 key-quarters of each query
    float l_run = l_part;
    l_run += __shfl_xor(l_run, 16, 64);
    l_run += __shfl_xor(l_run, 32, 64);

    // output: dim = dt*16 + q*4 + r, query = mr
    {
        float inv = 1.0f / l_run;
        int trow = qt * 64 + wv * 16 + mr;
        __hip_bfloat16* op = attn_out + (size_t)(b * T_ + trow) * D_ + h * HD_;
#pragma unroll
        for (int dt = 0; dt < 4; dt++) {
            uint2 val;
            val.x = pack2bf(o_acc[dt][0] * inv, o_acc[dt][1] * inv);
            val.y = pack2bf(o_acc[dt][2] * inv, o_acc[dt][3] * inv);
            *(uint2*)(op + dt * 16 + q * 4) = val;
        }
    }
}

// ---------------------------------------------------------------------------
// Kernel 5: h = rmsnorm(xn,w2)*gamma+beta; rotations+silu; out = xn + r - h.
// ---------------------------------------------------------------------------
__global__ __launch_bounds__(256) void final_kernel(
    const float* __restrict__ xn,
    const float* __restrict__ gamma,
    const float* __restrict__ beta,
    const float* __restrict__ w2,
    const float* __restrict__ angles,
    const float* __restrict__ gate,
    const float* __restrict__ bias,
    const int* __restrict__ pi,
    const int* __restrict__ pj,
    const int* __restrict__ flag,
    void* __restrict__ outp)
{
    __shared__ float rbuf[D_];
    __shared__ float red[4];
    int row = blockIdx.x, t = threadIdx.x;
    int f = *flag;
    float eps = f ? 1.1920929e-7f : 0.0078125f;
    const float4 xv = ((const float4*)(xn + (size_t)row * D_))[t];
    float x4[4] = {xv.x, xv.y, xv.z, xv.w};
    float ss = 0.f;
#pragma unroll
    for (int c = 0; c < 4; c++) ss += x4[c] * x4[c];
#pragma unroll
    for (int m = 32; m; m >>= 1) ss += __shfl_xor(ss, m, 64);
    int wv = t >> 6;
    if ((t & 63) == 0) red[wv] = ss;
    __syncthreads();
    float scale = rsqrtf((red[0] + red[1] + red[2] + red[3]) * (1.0f / D_) + eps);
    float hloc[4];
#pragma unroll
    for (int c = 0; c < 4; c++) {
        int e = t * 4 + c;
        float hv = x4[c] * scale * w2[e] * gamma[e] + beta[e];
        hloc[c] = hv;
        rbuf[e] = hv;
    }
    __syncthreads();
    for (int p = 0; p < NP_; p++) {
        float a = angles[p * P_ + t];
        float ca = __cosf(a), sa = __sinf(a);
        int ip = pi[p * P_ + t], jp = pj[p * P_ + t];
        float hi = rbuf[ip], hj = rbuf[jp];
        rbuf[ip] = hi * ca - hj * sa;
        rbuf[jp] = hi * sa + hj * ca;
        __syncthreads();
#pragma unroll
        for (int c = 0; c < 4; c++) {
            int e = t * 4 + c;
            float v = rbuf[e] * gate[p * D_ + e] + bias[p * D_ + e];
            rbuf[e] = v / (1.f + __expf(-v));
        }
        __syncthreads();
    }
#pragma unroll
    for (int c = 0; c < 4; c++) {
        int e = t * 4 + c;
        float ov = x4[c] + rbuf[e] - hloc[c];
        size_t idx = (size_t)row * D_ + e;
        if (f) ((float*)outp)[idx] = ov;
        else   ((__hip_bfloat16*)outp)[idx] = f2bf(ov);
    }
}

// ---------------------------------------------------------------------------
extern "C" void kernel_launch(void* const* d_in, const int* in_sizes, int n_in,
                              void* d_out, int out_size, void* d_ws, size_t ws_size,
                              hipStream_t stream)
{
    const void* x      = d_in[0];
    const void* gamma  = d_in[1];
    const void* beta   = d_in[2];
    const void* qkv_w  = d_in[3];
    const void* o_w    = d_in[4];
    const void* n1w    = d_in[5];
    const void* n2w    = d_in[6];
    const void* angles = d_in[7];
    const void* gate   = d_in[8];
    const void* bias   = d_in[9];
    const int* pi = (const int*)d_in[10];
    const int* pj = (const int*)d_in[11];

    const int M = B_ * T_;
    char* ws = (char*)d_ws;
    const size_t MB = 1u << 20;
    int*   flag   = (int*)ws;
    float* smalls = (float*)(ws + 4096);       // 11008 floats, 44 KB
    float* gf   = smalls;
    float* bf   = smalls + 1024;
    float* n2f  = smalls + 3072;
    float* angf = smalls + 4096;
    float* gtf  = smalls + 4864;
    float* bif  = smalls + 7936;
    __hip_bfloat16* wbf  = (__hip_bfloat16*)(ws + 17 * MB);  //  6 MB [3D,D]
    __hip_bfloat16* owbf = (__hip_bfloat16*)(ws + 23 * MB);  //  2 MB [D,D]
    __hip_bfloat16* h1   = (__hip_bfloat16*)(ws + 25 * MB);  //  8 MB [M,D] (h / attn out)
    __hip_bfloat16* qkv  = (__hip_bfloat16*)(ws + 33 * MB);  // 24 MB [M,3D]
    float*          xnew = (float*)         (ws + 33 * MB);  // 16 MB, aliases dead qkv

    detect_kernel<<<1, 256, 0, stream>>>((const unsigned short*)x, flag);

    prep_kernel<<<6187, 256, 0, stream>>>(
        x, qkv_w, o_w, gamma, beta, n1w, n2w, angles, gate, bias,
        flag, wbf, owbf, smalls, h1);

    gemm_bt_bf16_kernel<<<dim3(3 * D_ / 128, M / 128), 256, 0, stream>>>(
        h1, wbf, qkv, M, 3 * D_, D_, D_, SCALE2);

    attn_kernel<<<dim3(1024), 256, 0, stream>>>(qkv, h1);

    gemm_o64_resid_kernel<<<dim3(D_ / 64, M / 128), 256, 0, stream>>>(
        h1, owbf, x, flag, xnew, M, D_, D_);

    final_kernel<<<M, 256, 0, stream>>>(xnew, gf, bf, n2f, angf, gtf, bif,
                                        pi, pj, flag, d_out);
}

// Round 9
// 210.270 us; speedup vs baseline: 1.2509x; 1.1179x over previous
//
#include <hip/hip_runtime.h>
#include <hip/hip_bf16.h>

#define B_ 2
#define T_ 2048
#define D_ 1024
#define H_ 16
#define HD_ 64
#define NP_ 3
#define P_ 256

// log2(e)/sqrt(64): folded into Q in the QKV-GEMM epilogue; softmax in exp2 domain
#define SCALE2 0.18033688011112042f

typedef short bf16x8 __attribute__((ext_vector_type(8)));
typedef float f32x4 __attribute__((ext_vector_type(4)));

__device__ __forceinline__ float bf2f(__hip_bfloat16 v) { return __bfloat162float(v); }
__device__ __forceinline__ __hip_bfloat16 f2bf(float v) { return __float2bfloat16(v); }

// one v_cvt_pk_bf16_f32: dst.lo16 = bf16_rne(a), dst.hi16 = bf16_rne(b).
__device__ __forceinline__ unsigned pack2bf(float a, float b) {
    unsigned r;
    asm("v_cvt_pk_bf16_f32 %0, %1, %2" : "=v"(r) : "v"(a), "v"(b));
    return r;
}
__device__ __forceinline__ unsigned short f2bf_u(float v) {
    return (unsigned short)pack2bf(v, v);
}

#define GLOAD_LDS16(gp, lp) \
    __builtin_amdgcn_global_load_lds( \
        (const __attribute__((address_space(1))) void*)(gp), \
        (__attribute__((address_space(3))) void*)(lp), 16, 0, 0)

// ---------------------------------------------------------------------------
// Per-block input dtype detect (replaces the single-block detect kernel):
// sample the first 2048 shorts of x. fp32-as-shorts -> low halves have
// ~uniform mantissa bits => ~28% show exponent-field >= 0xB8 (~287 hits);
// genuine bf16 N(0,1) data shows 0. Threshold 8, same as before.
// ---------------------------------------------------------------------------
__device__ __forceinline__ int block_flag(const unsigned short* xs) {
    __shared__ int fred[4];
    int t = threadIdx.x;
    uint4 v = ((const uint4*)xs)[t];
    int bad = 0;
    unsigned w[4] = {v.x, v.y, v.z, v.w};
#pragma unroll
    for (int i = 0; i < 4; i++) {
        if ((((w[i] & 0xffffu) >> 7) & 0xFF) >= 0xB8) bad++;
        if ((((w[i] >> 16)     >> 7) & 0xFF) >= 0xB8) bad++;
    }
#pragma unroll
    for (int m = 32; m; m >>= 1) bad += __shfl_xor(bad, m, 64);
    if ((t & 63) == 0) fred[t >> 6] = bad;
    __syncthreads();
    return (fred[0] + fred[1] + fred[2] + fred[3]) >= 8;
}

// ---------------------------------------------------------------------------
// Merged prep kernel (one launch, all flag-dependent preprocessing):
//  blocks [0, 2048)       : qkv_w + o_w -> bf16, 8 elems/thread
//  blocks [2048, 6144)    : rmsnorm1 rows (params loaded raw w/ flag branch)
//  blocks [6144, 6187)    : 7 small fp32 param arrays -> contiguous block
// Each block self-computes the dtype flag; block 0 publishes it for the
// o-proj and final kernels (they run strictly later).
// ---------------------------------------------------------------------------
__global__ __launch_bounds__(256) void prep_kernel(
    const void* __restrict__ xraw,
    const void* __restrict__ qkvw, const void* __restrict__ ow,
    const void* __restrict__ g,  const void* __restrict__ b,
    const void* __restrict__ n1, const void* __restrict__ n2,
    const void* __restrict__ ang, const void* __restrict__ gt,
    const void* __restrict__ bi,
    int* __restrict__ flagp,
    __hip_bfloat16* __restrict__ wbf, __hip_bfloat16* __restrict__ owbf,
    float* __restrict__ smalls, __hip_bfloat16* __restrict__ out)
{
    int bid = blockIdx.x;
    int t = threadIdx.x;
    int f = block_flag((const unsigned short*)xraw);
    if (bid == 0 && t == 0) *flagp = f;

    if (bid < 2048) {
        // ---- weight conversion ----
        const int na = 3 * D_ * D_;
        int i8 = (bid * 256 + t) * 8;
        const void* src; __hip_bfloat16* dst; int off;
        if (i8 < na) { src = qkvw; dst = wbf; off = i8; }
        else         { src = ow;   dst = owbf; off = i8 - na; }
        if (f) {
            const float4* sp = (const float4*)((const float*)src + off);
            float4 v0 = sp[0], v1 = sp[1];
            uint4 o;
            o.x = pack2bf(v0.x, v0.y);
            o.y = pack2bf(v0.z, v0.w);
            o.z = pack2bf(v1.x, v1.y);
            o.w = pack2bf(v1.z, v1.w);
            *(uint4*)(dst + off) = o;
        } else {
            *(uint4*)(dst + off) = *(const uint4*)((const __hip_bfloat16*)src + off);
        }
        return;
    }
    if (bid < 6144) {
        // ---- rmsnorm1: h = rmsnorm(x,w)*gamma+beta (bf16 out) ----
        int row = bid - 2048;
        float eps = f ? 1.1920929e-7f : 0.0078125f;
        float v[4], ga[4], be[4], ww[4];
        if (f) {
            const float4 xv = ((const float4*)((const float*)xraw + (size_t)row * D_))[t];
            v[0] = xv.x; v[1] = xv.y; v[2] = xv.z; v[3] = xv.w;
            const float4 gv = ((const float4*)g)[t];
            ga[0] = gv.x; ga[1] = gv.y; ga[2] = gv.z; ga[3] = gv.w;
            const float4 bv = ((const float4*)b)[t];
            be[0] = bv.x; be[1] = bv.y; be[2] = bv.z; be[3] = bv.w;
            const float4 wv4 = ((const float4*)n1)[t];
            ww[0] = wv4.x; ww[1] = wv4.y; ww[2] = wv4.z; ww[3] = wv4.w;
        } else {
            const uint2 u = ((const uint2*)((const __hip_bfloat16*)xraw + (size_t)row * D_))[t];
            v[0] = __uint_as_float(u.x << 16);
            v[1] = __uint_as_float(u.x & 0xffff0000u);
            v[2] = __uint_as_float(u.y << 16);
            v[3] = __uint_as_float(u.y & 0xffff0000u);
#pragma unroll
            for (int c = 0; c < 4; c++) {
                int e = t * 4 + c;
                ga[c] = bf2f(((const __hip_bfloat16*)g)[e]);
                be[c] = bf2f(((const __hip_bfloat16*)b)[e]);
                ww[c] = bf2f(((const __hip_bfloat16*)n1)[e]);
            }
        }
        float ss = 0.f;
#pragma unroll
        for (int c = 0; c < 4; c++) ss += v[c] * v[c];
#pragma unroll
        for (int m = 32; m; m >>= 1) ss += __shfl_xor(ss, m, 64);
        __shared__ float red[4];
        int wv = t >> 6;
        if ((t & 63) == 0) red[wv] = ss;
        __syncthreads();
        float scale = rsqrtf((red[0] + red[1] + red[2] + red[3]) * (1.0f / D_) + eps);
        float o[4];
#pragma unroll
        for (int c = 0; c < 4; c++)
            o[c] = v[c] * scale * ww[c] * ga[c] + be[c];
        uint2 pkd;
        pkd.x = pack2bf(o[0], o[1]);
        pkd.y = pack2bf(o[2], o[3]);
        *(uint2*)(out + (size_t)row * D_ + t * 4) = pkd;
        return;
    }
    {
        // ---- small param arrays -> fp32 ----
        int i = (bid - 6144) * 256 + t;
        if (i >= 11008) return;
        const void* src; int off;
        if      (i < 1024) { src = g;   off = i; }
        else if (i < 2048) { src = b;   off = i - 1024; }
        else if (i < 3072) { src = n1;  off = i - 2048; }
        else if (i < 4096) { src = n2;  off = i - 3072; }
        else if (i < 4864) { src = ang; off = i - 4096; }
        else if (i < 7936) { src = gt;  off = i - 4864; }
        else               { src = bi;  off = i - 7936; }
        smalls[i] = f ? ((const float*)src)[off]
                      : bf2f(((const __hip_bfloat16*)src)[off]);
    }
}

// ---------------------------------------------------------------------------
// Kernel 2: C = A @ B^T bf16 out. 128x128, BK=64 (halves the per-K-step
// vmcnt(0)+barrier drains vs BK=32 -- the known ~20% m97-structure stall).
// 128B LDS rows would be a 16-way bank conflict on fragment reads, so the
// T2 pattern is applied: linear global_load_lds dest + XOR-preswizzled
// GLOBAL source chunk (chunk ^ (row&7)) + same XOR on the read side ->
// 2 lanes/bank (free). Per-element K-accumulation order is bit-identical
// to the BK=32 version (h=0 then h=1 = two former steps).
// ---------------------------------------------------------------------------
__global__ __launch_bounds__(256) void gemm_bt_bf16_kernel(
    const __hip_bfloat16* __restrict__ A,
    const __hip_bfloat16* __restrict__ Bm,
    __hip_bfloat16* __restrict__ C,
    int M, int N, int K, int nscale, float qscale)
{
    __shared__ __attribute__((aligned(16))) __hip_bfloat16 As[128 * 64];
    __shared__ __attribute__((aligned(16))) __hip_bfloat16 Bs[128 * 64];
    int tid = threadIdx.x;
    int bm = blockIdx.y, bn = blockIdx.x;
    int lane = tid & 63, wv = tid >> 6;
    int wm = wv >> 1, wn = wv & 1;
    int q = lane >> 4, mr = lane & 15;
    int m8 = mr & 7;

    f32x4 acc[4][4] = {};

    for (int k0 = 0; k0 < K; k0 += 64) {
#pragma unroll
        for (int s = 0; s < 4; s++) {
            int e = (s * 256 + tid) * 8;       // physical LDS halfword offset
            int r = e >> 6;                    // row 0..127
            int pc = (e >> 3) & 7;             // physical 8-elem chunk
            int gc = (pc ^ (r & 7)) * 8;       // pre-swizzled global column
            GLOAD_LDS16(&A[(size_t)(bm * 128 + r) * K + k0 + gc], &As[e]);
            GLOAD_LDS16(&Bm[(size_t)(bn * 128 + r) * K + k0 + gc], &Bs[e]);
        }
        __syncthreads();
#pragma unroll
        for (int h = 0; h < 2; h++) {
            bf16x8 af[4], bfr[4];
#pragma unroll
            for (int i = 0; i < 4; i++)
                af[i] = *(const bf16x8*)(&As[(wm * 64 + i * 16 + mr) * 64 + (((h * 4 + q) ^ m8) * 8)]);
#pragma unroll
            for (int j = 0; j < 4; j++)
                bfr[j] = *(const bf16x8*)(&Bs[(wn * 64 + j * 16 + mr) * 64 + (((h * 4 + q) ^ m8) * 8)]);
#pragma unroll
            for (int i = 0; i < 4; i++)
#pragma unroll
                for (int j = 0; j < 4; j++)
                    acc[i][j] = __builtin_amdgcn_mfma_f32_16x16x32_bf16(af[i], bfr[j], acc[i][j], 0, 0, 0);
        }
        __syncthreads();
    }

#pragma unroll
    for (int i = 0; i < 4; i++)
#pragma unroll
        for (int r = 0; r < 4; r++) {
            int m = bm * 128 + wm * 64 + i * 16 + q * 4 + r;
#pragma unroll
            for (int j = 0; j < 4; j++) {
                int n = bn * 128 + wn * 64 + j * 16 + mr;
                float vv = acc[i][j][r];
                if (n < nscale) vv *= qscale;
                ((unsigned short*)C)[(size_t)m * N + n] = f2bf_u(vv);
            }
        }
}

// ---------------------------------------------------------------------------
// o-proj GEMM, 128x64 tile, BK=64, same swizzled staging. 512 blocks = 2/CU.
// Residual read from raw input (flag-branched dtype), fp32 out.
// ---------------------------------------------------------------------------
__global__ __launch_bounds__(256) void gemm_o64_resid_kernel(
    const __hip_bfloat16* __restrict__ A,
    const __hip_bfloat16* __restrict__ Bm,
    const void* __restrict__ xraw,
    const int* __restrict__ flag,
    float* __restrict__ C,
    int M, int N, int K)
{
    __shared__ __attribute__((aligned(16))) __hip_bfloat16 As[128 * 64];
    __shared__ __attribute__((aligned(16))) __hip_bfloat16 Bs[64 * 64];
    int tid = threadIdx.x;
    int bn = blockIdx.x, bm = blockIdx.y;
    int lane = tid & 63, wv = tid >> 6;
    int q = lane >> 4, mr = lane & 15;
    int m8 = mr & 7;
    int f = *flag;

    f32x4 acc[2][4] = {};

    for (int k0 = 0; k0 < K; k0 += 64) {
#pragma unroll
        for (int s = 0; s < 4; s++) {
            int e = (s * 256 + tid) * 8;
            int r = e >> 6;
            int pc = (e >> 3) & 7;
            int gc = (pc ^ (r & 7)) * 8;
            GLOAD_LDS16(&A[(size_t)(bm * 128 + r) * K + k0 + gc], &As[e]);
        }
#pragma unroll
        for (int s = 0; s < 2; s++) {
            int e = (s * 256 + tid) * 8;
            int r = e >> 6;
            int pc = (e >> 3) & 7;
            int gc = (pc ^ (r & 7)) * 8;
            GLOAD_LDS16(&Bm[(size_t)(bn * 64 + r) * K + k0 + gc], &Bs[e]);
        }
        __syncthreads();
#pragma unroll
        for (int h = 0; h < 2; h++) {
            bf16x8 af[2], bfr[4];
#pragma unroll
            for (int i = 0; i < 2; i++)
                af[i] = *(const bf16x8*)(&As[(wv * 32 + i * 16 + mr) * 64 + (((h * 4 + q) ^ m8) * 8)]);
#pragma unroll
            for (int j = 0; j < 4; j++)
                bfr[j] = *(const bf16x8*)(&Bs[(j * 16 + mr) * 64 + (((h * 4 + q) ^ m8) * 8)]);
#pragma unroll
            for (int i = 0; i < 2; i++)
#pragma unroll
                for (int j = 0; j < 4; j++)
                    acc[i][j] = __builtin_amdgcn_mfma_f32_16x16x32_bf16(af[i], bfr[j], acc[i][j], 0, 0, 0);
        }
        __syncthreads();
    }

#pragma unroll
    for (int i = 0; i < 2; i++)
#pragma unroll
        for (int r = 0; r < 4; r++) {
            int m = bm * 128 + wv * 32 + i * 16 + q * 4 + r;
#pragma unroll
            for (int j = 0; j < 4; j++) {
                int n = bn * 64 + j * 16 + mr;
                size_t idx = (size_t)m * N + n;
                float rv = f ? ((const float*)xraw)[idx]
                             : bf2f(((const __hip_bfloat16*)xraw)[idx]);
                C[idx] = rv + acc[i][j][r];
            }
        }
}

// ---------------------------------------------------------------------------
// Kernel 3: causal flash attention, r9 structure (measured local optimum)
// + s_setprio(1/0) around the two MFMA clusters (T5; m191: +4-7% on attn
// with cross-block phase diversity; pure scheduling, no math change).
// Grid: 1024 balanced blocks (r6 mapping), 40KB LDS, 4 blocks/CU.
// ---------------------------------------------------------------------------
__global__ __launch_bounds__(256, 4) void attn_kernel(
    const __hip_bfloat16* __restrict__ qkv,
    __hip_bfloat16* __restrict__ attn_out)
{
    __shared__ __attribute__((aligned(16))) __hip_bfloat16 Ks[2][64 * 64];
    __shared__ __attribute__((aligned(16))) __hip_bfloat16 Vts[2][64 * 64]; // [dim][key]
    __shared__ __attribute__((aligned(16))) unsigned int Pd[4 * 512];      // P^T, 2KB/wave

    int id = blockIdx.x;                       // 0..1023
    int half = (id ^ (id >> 8)) & 1;
    int w4 = (id >> 1) & 15;
    int qt = half ? 31 - w4 : w4;              // query tile 0..31
    int bh = (id >> 5) & 31;
    int b = bh >> 4, h = bh & 15;
    int tid = threadIdx.x, lane = tid & 63, wv = tid >> 6;
    int q = lane >> 4, mr = lane & 15;
    int m8 = mr & 7;

    const size_t rs3 = 3 * D_;
    const __hip_bfloat16* qp = qkv + (size_t)(b * T_) * rs3 + h * HD_;
    const __hip_bfloat16* kp = qp + D_;
    const __hip_bfloat16* vp = qp + 2 * D_;

    // staging roles
    int sr = tid >> 2;              // K row (key) 0..63
    int sc = (tid & 3) * 16;        // K col start
    int lc0 = sc >> 3;
    int swk = sr & 7;
    int kk_ = (tid & 31) * 2;       // V key (even)
    int dd = (tid >> 5) * 8;        // V dim chunk base
    int vlc = kk_ >> 3, voff = kk_ & 7;

    // Q fragments: lane holds Q row (wv*16 + mr); these are the B-operand
    bf16x8 aq0, aq1;
    {
        const __hip_bfloat16* qrow = qp + (size_t)(qt * 64 + wv * 16 + mr) * rs3;
        aq0 = *(const bf16x8*)(qrow + q * 8);
        aq1 = *(const bf16x8*)(qrow + 32 + q * 8);
    }

    // prefetch K/V tile 0 and stage into buffer 0
    bf16x8 kr0 = *(const bf16x8*)(kp + (size_t)sr * rs3 + sc);
    bf16x8 kr1 = *(const bf16x8*)(kp + (size_t)sr * rs3 + sc + 8);
    bf16x8 vr0 = *(const bf16x8*)(vp + (size_t)kk_ * rs3 + dd);
    bf16x8 vr1 = *(const bf16x8*)(vp + (size_t)(kk_ + 1) * rs3 + dd);
    *(bf16x8*)(&Ks[0][sr * 64 + ((lc0 ^ swk) * 8)]) = kr0;
    *(bf16x8*)(&Ks[0][sr * 64 + (((lc0 + 1) ^ swk) * 8)]) = kr1;
    {
        unsigned int* vd = (unsigned int*)&Vts[0][0];
        union { bf16x8 v; unsigned u[4]; } ua, ub;
        ua.v = vr0; ub.v = vr1;
#pragma unroll
        for (int w = 0; w < 4; w++) {
            unsigned lo = __builtin_amdgcn_perm(ub.u[w], ua.u[w], 0x05040100u);
            unsigned hi = __builtin_amdgcn_perm(ub.u[w], ua.u[w], 0x07060302u);
            int i0 = 2 * w, i1 = 2 * w + 1;
            vd[((dd + i0) * 64 + ((vlc ^ i0) * 8 + voff)) >> 1] = lo;
            vd[((dd + i1) * 64 + ((vlc ^ i1) * 8 + voff)) >> 1] = hi;
        }
    }
    __syncthreads();

    float l_part = 0.f;                 // per-thread partial; reduced after loop
    f32x4 o_acc[4] = {};
    unsigned int* Pw = &Pd[wv * 512];
    int qloc = wv * 16 + mr;            // query row within 64-tile

    for (int s = 0; s <= qt; s++) {
        int buf = s & 1;

        // register prefetches for step s+1 (consumed after compute)
        if (s < qt) {
            int ktn = s + 1;
            kr0 = *(const bf16x8*)(kp + (size_t)(ktn * 64 + sr) * rs3 + sc);
            kr1 = *(const bf16x8*)(kp + (size_t)(ktn * 64 + sr) * rs3 + sc + 8);
            vr0 = *(const bf16x8*)(vp + (size_t)(ktn * 64 + kk_) * rs3 + dd);
            vr1 = *(const bf16x8*)(vp + (size_t)(ktn * 64 + kk_ + 1) * rs3 + dd);
        }

        // S^T strip: D[key][query], A = K-frag, B = Q-frag (swapped operands)
        f32x4 sv[4] = {};
        {
            const __hip_bfloat16* Kb = &Ks[buf][0];
            __builtin_amdgcn_s_setprio(1);
#pragma unroll
            for (int jn = 0; jn < 4; jn++)
                sv[jn] = __builtin_amdgcn_mfma_f32_16x16x32_bf16(
                    *(const bf16x8*)(&Kb[(jn * 16 + mr) * 64 + ((q ^ m8) * 8)]),
                    aq0, sv[jn], 0, 0, 0);
#pragma unroll
            for (int jn = 0; jn < 4; jn++)
                sv[jn] = __builtin_amdgcn_mfma_f32_16x16x32_bf16(
                    *(const bf16x8*)(&Kb[(jn * 16 + mr) * 64 + (((4 + q) ^ m8) * 8)]),
                    aq1, sv[jn], 0, 0, 0);
            __builtin_amdgcn_s_setprio(0);
        }

        if (s == qt) {   // causal mask: key (jn*16+q*4+r) > query (qloc)
#pragma unroll
            for (int jn = 0; jn < 4; jn++)
#pragma unroll
                for (int r = 0; r < 4; r++)
                    if (jn * 16 + q * 4 + r > qloc) sv[jn][r] = -1e30f;
        }

        // static-shift softmax: p = exp2(s); no max tracking, no rescale.
#pragma unroll
        for (int jn = 0; jn < 4; jn++)
#pragma unroll
            for (int r = 0; r < 4; r++) {
                float p = exp2f(sv[jn][r]);
                sv[jn][r] = p;
                l_part += p;
            }

        // P^T pack -> LDS: row = query (mr), dwords = key pairs, b64 writes.
        // Physical dword addr = mr*32 + ((dw4 ^ m8) << 2) + low2 (conflict-free).
#pragma unroll
        for (int jn = 0; jn < 4; jn++) {
            uint2 val;
            val.x = pack2bf(sv[jn][0], sv[jn][1]);
            val.y = pack2bf(sv[jn][2], sv[jn][3]);
            int dw4 = 2 * jn + (q >> 1);
            *(uint2*)(&Pw[mr * 32 + ((dw4 ^ m8) << 2) + 2 * (q & 1)]) = val;
        }

        // PV: O^T[dim][query] += V^T-frag (A) x P^T-frag (B)
        __builtin_amdgcn_s_setprio(1);
#pragma unroll
        for (int kk = 0; kk < 2; kk++) {
            bf16x8 bp = *(const bf16x8*)(&Pw[mr * 32 + (((4 * kk + q) ^ m8) << 2)]);
#pragma unroll
            for (int dt = 0; dt < 4; dt++) {
                bf16x8 bv = *(const bf16x8*)(&Vts[buf][(dt * 16 + mr) * 64 + (((kk * 4 + q) ^ m8) * 8)]);
                o_acc[dt] = __builtin_amdgcn_mfma_f32_16x16x32_bf16(bv, bp, o_acc[dt], 0, 0, 0);
            }
        }
        __builtin_amdgcn_s_setprio(0);

        // stage next tile into the other buffer
        if (s < qt) {
            *(bf16x8*)(&Ks[buf ^ 1][sr * 64 + ((lc0 ^ swk) * 8)]) = kr0;
            *(bf16x8*)(&Ks[buf ^ 1][sr * 64 + (((lc0 + 1) ^ swk) * 8)]) = kr1;
            unsigned int* vd = (unsigned int*)&Vts[buf ^ 1][0];
            union { bf16x8 v; unsigned u[4]; } ua, ub;
            ua.v = vr0; ub.v = vr1;
#pragma unroll
            for (int w = 0; w < 4; w++) {
                unsigned lo = __builtin_amdgcn_perm(ub.u[w], ua.u[w], 0x05040100u);
                unsigned hi = __builtin_amdgcn_perm(ub.u[w], ua.u[w], 0x07060302u);
                int i0 = 2 * w, i1 = 2 * w + 1;
                vd[((dd + i0) * 64 + ((vlc ^ i0) * 8 + voff)) >> 1] = lo;
                vd[((dd + i1) * 64 + ((vlc ^ i1) * 8 + voff)) >> 1] = hi;
            }
        }
        __syncthreads();
    }

    // final l reduction across the 4 key-quarters of each query
    float l_run = l_part;
    l_run += __shfl_xor(l_run, 16, 64);
    l_run += __shfl_xor(l_run, 32, 64);

    // output: dim = dt*16 + q*4 + r, query = mr
    {
        float inv = 1.0f / l_run;
        int trow = qt * 64 + wv * 16 + mr;
        __hip_bfloat16* op = attn_out + (size_t)(b * T_ + trow) * D_ + h * HD_;
#pragma unroll
        for (int dt = 0; dt < 4; dt++) {
            uint2 val;
            val.x = pack2bf(o_acc[dt][0] * inv, o_acc[dt][1] * inv);
            val.y = pack2bf(o_acc[dt][2] * inv, o_acc[dt][3] * inv);
            *(uint2*)(op + dt * 16 + q * 4) = val;
        }
    }
}

// ---------------------------------------------------------------------------
// Kernel 5: h = rmsnorm(xn,w2)*gamma+beta; rotations+silu; out = xn + r - h.
// ---------------------------------------------------------------------------
__global__ __launch_bounds__(256) void final_kernel(
    const float* __restrict__ xn,
    const float* __restrict__ gamma,
    const float* __restrict__ beta,
    const float* __restrict__ w2,
    const float* __restrict__ angles,
    const float* __restrict__ gate,
    const float* __restrict__ bias,
    const int* __restrict__ pi,
    const int* __restrict__ pj,
    const int* __restrict__ flag,
    void* __restrict__ outp)
{
    __shared__ float rbuf[D_];
    __shared__ float red[4];
    int row = blockIdx.x, t = threadIdx.x;
    int f = *flag;
    float eps = f ? 1.1920929e-7f : 0.0078125f;
    const float4 xv = ((const float4*)(xn + (size_t)row * D_))[t];
    float x4[4] = {xv.x, xv.y, xv.z, xv.w};
    float ss = 0.f;
#pragma unroll
    for (int c = 0; c < 4; c++) ss += x4[c] * x4[c];
#pragma unroll
    for (int m = 32; m; m >>= 1) ss += __shfl_xor(ss, m, 64);
    int wv = t >> 6;
    if ((t & 63) == 0) red[wv] = ss;
    __syncthreads();
    float scale = rsqrtf((red[0] + red[1] + red[2] + red[3]) * (1.0f / D_) + eps);
    float hloc[4];
#pragma unroll
    for (int c = 0; c < 4; c++) {
        int e = t * 4 + c;
        float hv = x4[c] * scale * w2[e] * gamma[e] + beta[e];
        hloc[c] = hv;
        rbuf[e] = hv;
    }
    __syncthreads();
    for (int p = 0; p < NP_; p++) {
        float a = angles[p * P_ + t];
        float ca = __cosf(a), sa = __sinf(a);
        int ip = pi[p * P_ + t], jp = pj[p * P_ + t];
        float hi = rbuf[ip], hj = rbuf[jp];
        rbuf[ip] = hi * ca - hj * sa;
        rbuf[jp] = hi * sa + hj * ca;
        __syncthreads();
#pragma unroll
        for (int c = 0; c < 4; c++) {
            int e = t * 4 + c;
            float v = rbuf[e] * gate[p * D_ + e] + bias[p * D_ + e];
            rbuf[e] = v / (1.f + __expf(-v));
        }
        __syncthreads();
    }
#pragma unroll
    for (int c = 0; c < 4; c++) {
        int e = t * 4 + c;
        float ov = x4[c] + rbuf[e] - hloc[c];
        size_t idx = (size_t)row * D_ + e;
        if (f) ((float*)outp)[idx] = ov;
        else   ((__hip_bfloat16*)outp)[idx] = f2bf(ov);
    }
}

// ---------------------------------------------------------------------------
extern "C" void kernel_launch(void* const* d_in, const int* in_sizes, int n_in,
                              void* d_out, int out_size, void* d_ws, size_t ws_size,
                              hipStream_t stream)
{
    const void* x      = d_in[0];
    const void* gamma  = d_in[1];
    const void* beta   = d_in[2];
    const void* qkv_w  = d_in[3];
    const void* o_w    = d_in[4];
    const void* n1w    = d_in[5];
    const void* n2w    = d_in[6];
    const void* angles = d_in[7];
    const void* gate   = d_in[8];
    const void* bias   = d_in[9];
    const int* pi = (const int*)d_in[10];
    const int* pj = (const int*)d_in[11];

    const int M = B_ * T_;
    char* ws = (char*)d_ws;
    const size_t MB = 1u << 20;
    int*   flag   = (int*)ws;
    float* smalls = (float*)(ws + 4096);       // 11008 floats, 44 KB
    float* gf   = smalls;
    float* bf   = smalls + 1024;
    float* n2f  = smalls + 3072;
    float* angf = smalls + 4096;
    float* gtf  = smalls + 4864;
    float* bif  = smalls + 7936;
    __hip_bfloat16* wbf  = (__hip_bfloat16*)(ws + 17 * MB);  //  6 MB [3D,D]
    __hip_bfloat16* owbf = (__hip_bfloat16*)(ws + 23 * MB);  //  2 MB [D,D]
    __hip_bfloat16* h1   = (__hip_bfloat16*)(ws + 25 * MB);  //  8 MB [M,D] (h / attn out)
    __hip_bfloat16* qkv  = (__hip_bfloat16*)(ws + 33 * MB);  // 24 MB [M,3D]
    float*          xnew = (float*)         (ws + 33 * MB);  // 16 MB, aliases dead qkv

    prep_kernel<<<6187, 256, 0, stream>>>(
        x, qkv_w, o_w, gamma, beta, n1w, n2w, angles, gate, bias,
        flag, wbf, owbf, smalls, h1);

    gemm_bt_bf16_kernel<<<dim3(3 * D_ / 128, M / 128), 256, 0, stream>>>(
        h1, wbf, qkv, M, 3 * D_, D_, D_, SCALE2);

    attn_kernel<<<dim3(1024), 256, 0, stream>>>(qkv, h1);

    gemm_o64_resid_kernel<<<dim3(D_ / 64, M / 128), 256, 0, stream>>>(
        h1, owbf, x, flag, xnew, M, D_, D_);

    final_kernel<<<M, 256, 0, stream>>>(xnew, gf, bf, n2f, angf, gtf, bif,
                                        pi, pj, flag, d_out);
}